// Round 2
// baseline (660.221 us; speedup 1.0000x reference)
//
#include <hip/hip_runtime.h>
#include <hip/hip_bf16.h>

// Problem constants: x is (B=64, C=256, H=56, W=56) fp32.
#define B_   64
#define C_   256
#define BC   (B_ * C_)      // 16384 planes
#define CS   64             // squeeze channels
#define HW   3136           // 56*56
#define HW4  784            // HW / 4 (float4 count per plane)

__device__ __forceinline__ float fmin4(float4 v) {
    return fminf(fminf(v.x, v.y), fminf(v.z, v.w));
}
__device__ __forceinline__ float fmax4(float4 v) {
    return fmaxf(fmaxf(v.x, v.y), fmaxf(v.z, v.w));
}

// Kernel 1: per-plane sum / min / max. One block per (b,c) plane.
__global__ __launch_bounds__(256) void k_pool(const float* __restrict__ x,
                                              float* __restrict__ pooled,
                                              float* __restrict__ xmn,
                                              float* __restrict__ xmx) {
    const int bc = blockIdx.x;
    const float4* xp = (const float4*)(x + (size_t)bc * HW);
    const int t = threadIdx.x;

    float sum = 0.0f;
    float mn = 3.402823466e38f;
    float mx = -3.402823466e38f;
    for (int i = t; i < HW4; i += 256) {
        float4 v = xp[i];
        sum += (v.x + v.y) + (v.z + v.w);
        mn = fminf(mn, fmin4(v));
        mx = fmaxf(mx, fmax4(v));
    }
    // wave64 reduction
    for (int off = 32; off > 0; off >>= 1) {
        sum += __shfl_down(sum, off, 64);
        mn = fminf(mn, __shfl_down(mn, off, 64));
        mx = fmaxf(mx, __shfl_down(mx, off, 64));
    }
    __shared__ float ssum[4], smn[4], smx[4];
    const int wave = t >> 6, lane = t & 63;
    if (lane == 0) { ssum[wave] = sum; smn[wave] = mn; smx[wave] = mx; }
    __syncthreads();
    if (t == 0) {
        float S  = (ssum[0] + ssum[1]) + (ssum[2] + ssum[3]);
        float MN = fminf(fminf(smn[0], smn[1]), fminf(smn[2], smn[3]));
        float MX = fmaxf(fmaxf(smx[0], smx[1]), fmaxf(smx[2], smx[3]));
        pooled[bc] = S / (float)HW;
        xmn[bc] = MN;
        xmx[bc] = MX;
    }
}

// Kernel 2 (single block): fc1+ReLU, fc2+hardsigmoid -> g; then since g>=0,
// global min(out) = min_bc(g*xmin), max(out) = max_bc(g*xmx). Compute s, z.
__global__ __launch_bounds__(256) void k_fc(const float* __restrict__ pooled,
                                            const float* __restrict__ xmn,
                                            const float* __restrict__ xmx,
                                            const float* __restrict__ w1,
                                            const float* __restrict__ b1,
                                            const float* __restrict__ w2,
                                            const float* __restrict__ b2,
                                            const float* __restrict__ act_range,
                                            float* __restrict__ g,
                                            float* __restrict__ sz) {
    __shared__ float h[B_ * CS];   // 16 KB
    const int t = threadIdx.x;

    // fc1: h[b,s] = relu(sum_c pooled[b,c] * w1[s,c] + b1[s]); rows are
    // contiguous so the dot product vectorizes as float4.
    for (int i = t; i < B_ * CS; i += 256) {
        const int b = i >> 6, s = i & 63;
        const float4* pr = (const float4*)(pooled + b * C_);
        const float4* wr = (const float4*)(w1 + s * C_);
        float acc = b1[s];
        #pragma unroll 8
        for (int c = 0; c < C_ / 4; ++c) {
            float4 p = pr[c], w = wr[c];
            acc += p.x * w.x + p.y * w.y + p.z * w.z + p.w * w.w;
        }
        h[i] = fmaxf(acc, 0.0f);
    }
    __syncthreads();

    // fc2 + hardsigmoid; fold per-plane min/max of out via g*xmn / g*xmx
    float mn = 3.402823466e38f;
    float mx = -3.402823466e38f;
    for (int i = t; i < BC; i += 256) {
        const int b = i >> 8, c = i & 255;
        const float4* hr = (const float4*)(h + b * CS);
        const float4* wr = (const float4*)(w2 + c * CS);
        float acc = b2[c];
        #pragma unroll 8
        for (int s = 0; s < CS / 4; ++s) {
            float4 hv = hr[s], w = wr[s];
            acc += hv.x * w.x + hv.y * w.y + hv.z * w.z + hv.w * w.w;
        }
        float gg = fminf(fmaxf(acc / 6.0f + 0.5f, 0.0f), 1.0f);
        g[i] = gg;
        mn = fminf(mn, gg * xmn[i]);   // g>=0 so this is min over the plane
        mx = fmaxf(mx, gg * xmx[i]);
    }
    for (int off = 32; off > 0; off >>= 1) {
        mn = fminf(mn, __shfl_down(mn, off, 64));
        mx = fmaxf(mx, __shfl_down(mx, off, 64));
    }
    __shared__ float smn[4], smx[4];
    const int wave = t >> 6, lane = t & 63;
    if (lane == 0) { smn[wave] = mn; smx[wave] = mx; }
    __syncthreads();
    if (t == 0) {
        float rmin = fminf(fminf(smn[0], smn[1]), fminf(smn[2], smn[3]));
        float rmax = fmaxf(fmaxf(smx[0], smx[1]), fmaxf(smx[2], smx[3]));
        float new_min = act_range[0] * 0.999f + rmin * 0.001f;
        float new_max = act_range[1] * 0.999f + rmax * 0.001f;
        float s = (new_max - new_min) / 255.0f;
        float z = -rintf(new_min / s);   // rintf = round-half-even = jnp.round
        sz[0] = s;
        sz[1] = z;
    }
}

__device__ __forceinline__ float quant1(float o, float s, float z) {
    float q = rintf(o / s + z);
    q = fminf(fmaxf(q, 0.0f), 255.0f);
    return (q - z) * s;
}

// Kernel 3: out = fakequant(x * g[b,c]). One block per plane, float4 I/O.
__global__ __launch_bounds__(256) void k_quant(const float* __restrict__ x,
                                               const float* __restrict__ g,
                                               const float* __restrict__ sz,
                                               float* __restrict__ out) {
    const int bc = blockIdx.x;
    const float gv = g[bc];
    const float s = sz[0];
    const float z = sz[1];
    const float4* xp = (const float4*)(x + (size_t)bc * HW);
    float4* op = (float4*)(out + (size_t)bc * HW);
    const int t = threadIdx.x;
    for (int i = t; i < HW4; i += 256) {
        float4 v = xp[i];
        float4 r;
        r.x = quant1(v.x * gv, s, z);
        r.y = quant1(v.y * gv, s, z);
        r.z = quant1(v.z * gv, s, z);
        r.w = quant1(v.w * gv, s, z);
        op[i] = r;
    }
}

extern "C" void kernel_launch(void* const* d_in, const int* in_sizes, int n_in,
                              void* d_out, int out_size, void* d_ws, size_t ws_size,
                              hipStream_t stream) {
    const float* x         = (const float*)d_in[0];
    const float* w1        = (const float*)d_in[1];
    const float* b1        = (const float*)d_in[2];
    const float* w2        = (const float*)d_in[3];
    const float* b2        = (const float*)d_in[4];
    const float* act_range = (const float*)d_in[5];
    float* out = (float*)d_out;

    // workspace layout (floats): pooled[16384] | xmn[16384] | xmx[16384] | g[16384] | sz[2]
    float* ws     = (float*)d_ws;
    float* pooled = ws;
    float* xmn    = ws + BC;
    float* xmx    = ws + 2 * BC;
    float* g      = ws + 3 * BC;
    float* sz     = ws + 4 * BC;

    k_pool<<<BC, 256, 0, stream>>>(x, pooled, xmn, xmx);
    k_fc<<<1, 256, 0, stream>>>(pooled, xmn, xmx, w1, b1, w2, b2, act_range, g, sz);
    k_quant<<<BC, 256, 0, stream>>>(x, g, sz, out);
}

// Round 4
// 386.372 us; speedup vs baseline: 1.7088x; 1.7088x over previous
//
#include <hip/hip_runtime.h>
#include <hip/hip_bf16.h>

// Problem constants: x is (B=64, C=256, H=56, W=56) fp32.
#define B_   64
#define C_   256
#define BC   (B_ * C_)      // 16384 planes
#define CS   64             // squeeze channels
#define HW   3136           // 56*56
#define HW4  784            // HW / 4 (float4 count per plane)

typedef float floatx4 __attribute__((ext_vector_type(4)));  // native vec for nt-store

__device__ __forceinline__ float fmin4(float4 v) {
    return fminf(fminf(v.x, v.y), fminf(v.z, v.w));
}
__device__ __forceinline__ float fmax4(float4 v) {
    return fmaxf(fmaxf(v.x, v.y), fmaxf(v.z, v.w));
}

// Kernel 1: per-plane sum / min / max. One block per (b,c) plane.
__global__ __launch_bounds__(256) void k_pool(const float* __restrict__ x,
                                              float* __restrict__ pooled,
                                              float* __restrict__ xmn,
                                              float* __restrict__ xmx) {
    const int bc = blockIdx.x;
    const float4* xp = (const float4*)(x + (size_t)bc * HW);
    const int t = threadIdx.x;

    float sum = 0.0f;
    float mn = 3.402823466e38f;
    float mx = -3.402823466e38f;
    for (int i = t; i < HW4; i += 256) {
        float4 v = xp[i];
        sum += (v.x + v.y) + (v.z + v.w);
        mn = fminf(mn, fmin4(v));
        mx = fmaxf(mx, fmax4(v));
    }
    for (int off = 32; off > 0; off >>= 1) {
        sum += __shfl_down(sum, off, 64);
        mn = fminf(mn, __shfl_down(mn, off, 64));
        mx = fmaxf(mx, __shfl_down(mx, off, 64));
    }
    __shared__ float ssum[4], smn[4], smx[4];
    const int wave = t >> 6, lane = t & 63;
    if (lane == 0) { ssum[wave] = sum; smn[wave] = mn; smx[wave] = mx; }
    __syncthreads();
    if (t == 0) {
        float S  = (ssum[0] + ssum[1]) + (ssum[2] + ssum[3]);
        float MN = fminf(fminf(smn[0], smn[1]), fminf(smn[2], smn[3]));
        float MX = fmaxf(fmaxf(smx[0], smx[1]), fmaxf(smx[2], smx[3]));
        pooled[bc] = S / (float)HW;
        xmn[bc] = MN;
        xmx[bc] = MX;
    }
}

// Kernel 2a: fc1. One block per batch b (64 blocks). h[b,s] = relu(pooled[b,:]·w1[s,:] + b1[s]).
// 256 threads = 64 outputs × 4 partial-dots; pooled row staged in LDS.
__global__ __launch_bounds__(256) void k_fc1(const float* __restrict__ pooled,
                                             const float* __restrict__ w1,
                                             const float* __restrict__ b1,
                                             float* __restrict__ h) {
    const int b = blockIdx.x;
    const int t = threadIdx.x;
    __shared__ float p[C_];
    __shared__ float part[4][CS];
    p[t] = pooled[b * C_ + t];
    __syncthreads();

    const int s = t & 63, q = t >> 6;            // wave q handles quarter q
    const float4* wr = (const float4*)(w1 + s * C_ + q * 64);
    const float4* pr = (const float4*)(p + q * 64);
    float acc = 0.0f;
    #pragma unroll
    for (int k = 0; k < 16; ++k) {
        float4 w = wr[k], pv = pr[k];
        acc += w.x * pv.x + w.y * pv.y + w.z * pv.z + w.w * pv.w;
    }
    part[q][s] = acc;
    __syncthreads();
    if (t < CS) {
        float a = (part[0][t] + part[1][t]) + (part[2][t] + part[3][t]) + b1[t];
        h[b * CS + t] = fmaxf(a, 0.0f);
    }
}

// Kernel 2b: fc2 + hardsigmoid -> g, plus per-block (per-b) min/max of out
// folded via g*xmn / g*xmx (valid since g >= 0). One block per batch b.
__global__ __launch_bounds__(256) void k_fc2(const float* __restrict__ h,
                                             const float* __restrict__ xmn,
                                             const float* __restrict__ xmx,
                                             const float* __restrict__ w2,
                                             const float* __restrict__ b2,
                                             float* __restrict__ g,
                                             float* __restrict__ pmn,
                                             float* __restrict__ pmx) {
    const int b = blockIdx.x;
    const int t = threadIdx.x;
    __shared__ float hs[CS];
    if (t < CS) hs[t] = h[b * CS + t];
    __syncthreads();

    const float4* wr = (const float4*)(w2 + t * CS);
    const float4* hr = (const float4*)hs;
    float acc = b2[t];
    #pragma unroll
    for (int k = 0; k < 16; ++k) {
        float4 w = wr[k], hv = hr[k];
        acc += w.x * hv.x + w.y * hv.y + w.z * hv.z + w.w * hv.w;
    }
    float gg = fminf(fmaxf(acc / 6.0f + 0.5f, 0.0f), 1.0f);
    const int i = b * C_ + t;
    g[i] = gg;
    float mn = gg * xmn[i];
    float mx = gg * xmx[i];
    for (int off = 32; off > 0; off >>= 1) {
        mn = fminf(mn, __shfl_down(mn, off, 64));
        mx = fmaxf(mx, __shfl_down(mx, off, 64));
    }
    __shared__ float smn[4], smx[4];
    const int wave = t >> 6, lane = t & 63;
    if (lane == 0) { smn[wave] = mn; smx[wave] = mx; }
    __syncthreads();
    if (t == 0) {
        pmn[b] = fminf(fminf(smn[0], smn[1]), fminf(smn[2], smn[3]));
        pmx[b] = fmaxf(fmaxf(smx[0], smx[1]), fmaxf(smx[2], smx[3]));
    }
}

// Kernel 2c: final scalar reduce + EMA + quant params (s, z, 1/s). One wave.
__global__ __launch_bounds__(64) void k_sz(const float* __restrict__ pmn,
                                           const float* __restrict__ pmx,
                                           const float* __restrict__ act_range,
                                           float* __restrict__ sz) {
    const int t = threadIdx.x;
    float mn = pmn[t];
    float mx = pmx[t];
    for (int off = 32; off > 0; off >>= 1) {
        mn = fminf(mn, __shfl_down(mn, off, 64));
        mx = fmaxf(mx, __shfl_down(mx, off, 64));
    }
    if (t == 0) {
        float new_min = act_range[0] * 0.999f + mn * 0.001f;
        float new_max = act_range[1] * 0.999f + mx * 0.001f;
        float s = (new_max - new_min) / 255.0f;
        float z = -rintf(new_min / s);   // rintf = round-half-even = jnp.round
        sz[0] = s;
        sz[1] = z;
        sz[2] = 1.0f / s;
    }
}

__device__ __forceinline__ float quant1(float o, float s, float z, float inv_s) {
    float q = rintf(__builtin_fmaf(o, inv_s, z));
    q = fminf(fmaxf(q, 0.0f), 255.0f);
    return (q - z) * s;
}

// Kernel 3: out = fakequant(x * g[b,c]). One block per plane, float4 I/O.
// Non-temporal stores: out is write-once; keep x resident in L2/L3.
__global__ __launch_bounds__(256) void k_quant(const float* __restrict__ x,
                                               const float* __restrict__ g,
                                               const float* __restrict__ sz,
                                               float* __restrict__ out) {
    const int bc = blockIdx.x;
    const float gv = g[bc];
    const float s = sz[0];
    const float z = sz[1];
    const float inv_s = sz[2];
    const float4* xp = (const float4*)(x + (size_t)bc * HW);
    floatx4* op = (floatx4*)(out + (size_t)bc * HW);
    const int t = threadIdx.x;
    for (int i = t; i < HW4; i += 256) {
        float4 v = xp[i];
        floatx4 r;
        r.x = quant1(v.x * gv, s, z, inv_s);
        r.y = quant1(v.y * gv, s, z, inv_s);
        r.z = quant1(v.z * gv, s, z, inv_s);
        r.w = quant1(v.w * gv, s, z, inv_s);
        __builtin_nontemporal_store(r, op + i);
    }
}

extern "C" void kernel_launch(void* const* d_in, const int* in_sizes, int n_in,
                              void* d_out, int out_size, void* d_ws, size_t ws_size,
                              hipStream_t stream) {
    const float* x         = (const float*)d_in[0];
    const float* w1        = (const float*)d_in[1];
    const float* b1        = (const float*)d_in[2];
    const float* w2        = (const float*)d_in[3];
    const float* b2        = (const float*)d_in[4];
    const float* act_range = (const float*)d_in[5];
    float* out = (float*)d_out;

    // ws floats: pooled[16384] | xmn[16384] | xmx[16384] | g[16384] | h[4096] | pmn[64] | pmx[64] | sz[3]
    float* ws     = (float*)d_ws;
    float* pooled = ws;
    float* xmn    = ws + BC;
    float* xmx    = ws + 2 * BC;
    float* g      = ws + 3 * BC;
    float* h      = ws + 4 * BC;
    float* pmn    = h + B_ * CS;
    float* pmx    = pmn + B_;
    float* sz     = pmx + B_;

    k_pool <<<BC, 256, 0, stream>>>(x, pooled, xmn, xmx);
    k_fc1  <<<B_, 256, 0, stream>>>(pooled, w1, b1, h);
    k_fc2  <<<B_, 256, 0, stream>>>(h, xmn, xmx, w2, b2, g, pmn, pmx);
    k_sz   <<<1, 64, 0, stream>>>(pmn, pmx, act_range, sz);
    k_quant<<<BC, 256, 0, stream>>>(x, g, sz, out);
}